// Round 7
// baseline (141.802 us; speedup 1.0000x reference)
//
#include <hip/hip_runtime.h>
#include <hip/hip_bf16.h>

// ---------------------------------------------------------------------------
// HiddenEdgeDistanceMLP on MI355X (gfx950)
//
// reference:  s = s_lig[l] + s_poc[p]          [E,256]
//             h1 = silu(s @ W1.T + b1)         [E,128]
//             h2 = silu(h1 @ W2.T + b2)        [E,64]
//             out = relu(h2 @ W3.T + b3)       [E]
//
// v19 (R6): POCKET ROWS -> REGISTERS; LDS = exactly 32 KB -> 5 blocks/CU.
//   R5 post-mortem: zl->LDS cut VGPR 88->68 and won 3.7us, but 40.5KB LDS
//   caps 3 blocks/CU (~2.4 waves/SIMD measured); busy still ~33us with
//   ~14us latency idle. Issue-floor model: trans pipe 12.8us || main VALU
//   ~20us -> floor ~22-25us, reachable only with >=4 waves/SIMD.
//   Fix: pocket tile back to per-lane regs (lane c holds pocket row c,
//   pk[4][2] = 32 VGPR — R2's proven-correct pattern; R2's regression was
//   the W2 reg file on TOP of this, which stays in LDS here). LDS becomes
//   w2s(16384) + zl(16384) = 32768 B exactly; 5 x 32768 = 163840 = full
//   160KiB -> 5 blocks/CU, ~4-5 waves/SIMD. Also removes 2 of 6
//   ds_read_b128 per ks (pocket reads become register reads).
//   Math BITWISE identical to v18 (pk regs hold the same f32 Z bits the
//   LDS tile held; silu/RHU-pack/MFMA chain order untouched) -> absmax
//   expected exactly 0.001953125.
// v18/v17 mechanisms kept: block=(b,jt) grid 1280, zl[32][128] ligand tile
//   in LDS (16-lane broadcast reads), zero barriers after the initial one,
//   2-atoms-per-K-pass, b2 folded into acc init, single rhu-bf16 h1 +
//   1 MFMA/nt, W2 B-frags fragment-ordered in LDS, DPP rowsum, perm
//   packing, no min-waves bound (VGPR cliff -> spills).
// ---------------------------------------------------------------------------

#define B_CPLX   128
#define NLB      32
#define NPB      160
#define SDIM     256
#define H1DIM    128
#define NL_TOT   (B_CPLX * NLB)         // 4096
#define NP_TOT   (B_CPLX * NPB)         // 20480
#define NROWS    (NL_TOT + NP_TOT)      // 24576
#define E_TOT    (B_CPLX * NLB * NPB)   // 655360

#define W1_LDS_STRIDE 264               // 256 + 8 bf16 pad
#define JT_CHUNK 16                     // pocket rows per block

#define EDGE_BLOCKS (B_CPLX * 10)       // 1280 = (b, jt)

typedef __bf16 bf16x8 __attribute__((ext_vector_type(8)));
typedef unsigned short ushortx8 __attribute__((ext_vector_type(8)));
typedef unsigned short ushortx4 __attribute__((ext_vector_type(4)));
typedef unsigned uintx4 __attribute__((ext_vector_type(4)));
typedef float f32x4 __attribute__((ext_vector_type(4)));

__device__ __forceinline__ unsigned short f2bf(float f) {
    unsigned u = __builtin_bit_cast(unsigned, f);
    u += 0x7FFFu + ((u >> 16) & 1u);          // round-to-nearest-even
    return (unsigned short)(u >> 16);
}

// v_perm_b32: pack hi16(x0) low, hi16(x1) high (1 op)
__device__ __forceinline__ unsigned perm_hi16u(unsigned u0, unsigned u1) {
    return __builtin_amdgcn_perm(u1, u0, 0x07060302u);
}

// round-half-up bf16 pair pack: bitpattern + 0x8000 then take hi16.
__device__ __forceinline__ unsigned pack2_rhu(float x0, float x1) {
    unsigned u0 = __builtin_bit_cast(unsigned, x0) + 0x8000u;
    unsigned u1 = __builtin_bit_cast(unsigned, x1) + 0x8000u;
    return perm_hi16u(u0, u1);
}

__device__ __forceinline__ bf16x8 pack8_rhu(const float* x) {
    uintx4 h;
#pragma unroll
    for (int j = 0; j < 4; ++j) h[j] = pack2_rhu(x[2 * j], x[2 * j + 1]);
    return __builtin_bit_cast(bf16x8, h);
}

// hi/lo exact split (proj only): hi = trunc bf16, lo = bf16(x - hi)
__device__ __forceinline__ void pack_split(const float* x, bf16x8& hi, bf16x8& lo) {
    uintx4 h, l;
#pragma unroll
    for (int j = 0; j < 4; ++j) {
        float x0 = x[2 * j], x1 = x[2 * j + 1];
        unsigned u0 = __builtin_bit_cast(unsigned, x0);
        unsigned u1 = __builtin_bit_cast(unsigned, x1);
        h[j] = perm_hi16u(u0, u1);
        float hf0 = __builtin_bit_cast(float, u0 & 0xFFFF0000u);
        float hf1 = __builtin_bit_cast(float, u1 & 0xFFFF0000u);
        l[j] = pack2_rhu(x0 - hf0, x1 - hf1);
    }
    hi = __builtin_bit_cast(bf16x8, h);
    lo = __builtin_bit_cast(bf16x8, l);
}

__device__ __forceinline__ float fast_silu(float x) {
    return x * __builtin_amdgcn_rcpf(1.0f + __expf(-x));
}

// full-rate 16-lane row reduction: v_add_f32 + dpp row_ror 1,2,4,8
__device__ __forceinline__ float rowsum16(float s) {
    int b;
    b = __builtin_bit_cast(int, s);
    b = __builtin_amdgcn_update_dpp(b, b, 0x121, 0xF, 0xF, false);  // ror:1
    s += __builtin_bit_cast(float, b);
    b = __builtin_bit_cast(int, s);
    b = __builtin_amdgcn_update_dpp(b, b, 0x122, 0xF, 0xF, false);  // ror:2
    s += __builtin_bit_cast(float, b);
    b = __builtin_bit_cast(int, s);
    b = __builtin_amdgcn_update_dpp(b, b, 0x124, 0xF, 0xF, false);  // ror:4
    s += __builtin_bit_cast(float, b);
    b = __builtin_bit_cast(int, s);
    b = __builtin_amdgcn_update_dpp(b, b, 0x128, 0xF, 0xF, false);  // ror:8
    s += __builtin_bit_cast(float, b);
    return s;
}

// ---------------------------------------------------------------------------
// Kernel 1: Z[m][n] = X[m] @ W1[n] (+ b1[n] if m is a ligand row)
//   768 blocks = 384 row-tile groups x 2 N-halves; hi/lo split -> Z ~exact.
//   (verbatim v12)
// ---------------------------------------------------------------------------
__global__ __launch_bounds__(256) void proj_kernel(
    const float* __restrict__ s_lig, const float* __restrict__ s_poc,
    const float* __restrict__ W1,    const float* __restrict__ b1,
    float* __restrict__ Z)
{
    __shared__ unsigned short w1s[64 * W1_LDS_STRIDE];   // 33.8 KB

    const int tid  = threadIdx.x;
    const int tg   = blockIdx.x >> 1;             // row-tile group 0..383
    const int half = blockIdx.x & 1;              // N half

    {
        const f32x4* w4 = (const f32x4*)(W1 + (size_t)half * 64 * SDIM);  // 4096 units
#pragma unroll
        for (int r = 0; r < 2; ++r) {
            f32x4 t[8];
#pragma unroll
            for (int s = 0; s < 8; ++s) t[s] = w4[tid + (r * 8 + s) * 256];
#pragma unroll
            for (int s = 0; s < 8; ++s) {
                const int u = tid + (r * 8 + s) * 256;
                const int n = u >> 6;             // 64 f32x4 per 256-col row
                const int k4 = u & 63;
                ushortx4 us;
#pragma unroll
                for (int j = 0; j < 4; ++j) us[j] = f2bf(t[s][j]);
                *(ushortx4*)(&w1s[n * W1_LDS_STRIDE + k4 * 4]) = us;
            }
        }
    }
    __syncthreads();

    const int lane = tid & 63;
    const int widx = tid >> 6;
    const int c    = lane & 15;
    const int q    = lane >> 4;
    const int tile = tg * 4 + widx;               // 0..1535
    const int row  = tile * 16 + c;

    const float* src = (row < NL_TOT) ? (s_lig + (size_t)row * SDIM)
                                      : (s_poc + (size_t)(row - NL_TOT) * SDIM);

    f32x4 acc[4];
#pragma unroll
    for (int nt = 0; nt < 4; ++nt) acc[nt] = (f32x4){0.f, 0.f, 0.f, 0.f};

#pragma unroll
    for (int ks = 0; ks < 8; ++ks) {              // K = 256 = 8 x 32
        const int k0 = ks * 32 + q * 8;
        f32x4 xa = *reinterpret_cast<const f32x4*>(src + k0);
        f32x4 xb = *reinterpret_cast<const f32x4*>(src + k0 + 4);
        float xv[8] = {xa[0], xa[1], xa[2], xa[3], xb[0], xb[1], xb[2], xb[3]};
        bf16x8 ahi, alo;
        pack_split(xv, ahi, alo);
        bf16x8 bfrag[4];
#pragma unroll
        for (int nt = 0; nt < 4; ++nt)
            bfrag[nt] = *reinterpret_cast<const bf16x8*>(
                &w1s[(nt * 16 + c) * W1_LDS_STRIDE + k0]);
#pragma unroll
        for (int nt = 0; nt < 4; ++nt)            // hi pass (dep distance 4)
            acc[nt] = __builtin_amdgcn_mfma_f32_16x16x32_bf16(ahi, bfrag[nt], acc[nt], 0, 0, 0);
#pragma unroll
        for (int nt = 0; nt < 4; ++nt)            // lo pass
            acc[nt] = __builtin_amdgcn_mfma_f32_16x16x32_bf16(alo, bfrag[nt], acc[nt], 0, 0, 0);
    }

    // C/D layout: col n' = lane&15, row m = q*4 + reg
    const int mb = tile * 16 + q * 4;
#pragma unroll
    for (int nt = 0; nt < 4; ++nt) {
        const int n = half * 64 + nt * 16 + c;
        const float bias = b1[n];
#pragma unroll
        for (int r = 0; r < 4; ++r) {
            const int m = mb + r;
            float v = acc[nt][r];
            if (m < NL_TOT) v += bias;            // fold b1 into ligand rows only
            Z[(size_t)m * H1DIM + n] = v;
        }
    }
}

// ---------------------------------------------------------------------------
// Kernel 2: block = (complex b, pocket chunk jt); 1280 blocks x 4 waves.
//   Ligand rows in LDS (zl, shared); pocket rows in per-lane REGISTERS
//   (lane c holds pocket row c). LDS = 32768 B exactly -> 5 blocks/CU.
//   ZERO barriers after the initial one. Math verbatim v18.
// ---------------------------------------------------------------------------
__global__ __launch_bounds__(256) void edge_kernel(
    const float* __restrict__ Z,
    const float* __restrict__ W2, const float* __restrict__ b2,
    const float* __restrict__ W3, const float* __restrict__ b3,
    float* __restrict__ out)
{
    __shared__ float zl[NLB * H1DIM];                     // 16384 B, stride 128
    __shared__ unsigned short w2s[16 * 64 * 8];           // 16384 B frag-ordered
    // total exactly 32768 B -> 5 blocks/CU (5 x 32768 = 163840 = 160 KiB)

    const int tid = threadIdx.x;
    const int b   = blockIdx.x / 10;
    const int jt  = blockIdx.x - b * 10;          // 0..9

    // stage W2 as bf16 B-fragments, fragment-ordered (once per block):
    //   slot = chunk*64 + lane, chunk = nt*4 + ks;
    //   frag(lane) = W2[n = nt*16 + (lane&15)][ks*32 + (lane>>4)*8 .. +8]
    {
#pragma unroll
        for (int s = 0; s < 4; ++s) {
            const int slot   = tid + s * 256;             // 0..1023
            const int lane_s = slot & 63;
            const int chunk  = slot >> 6;
            const int nt     = chunk >> 2;
            const int ks     = chunk & 3;
            const int n      = nt * 16 + (lane_s & 15);
            const int k0     = ks * 32 + (lane_s >> 4) * 8;
            const float* wsrc = W2 + (size_t)n * H1DIM + k0;
            f32x4 wa = *(const f32x4*)wsrc;
            f32x4 wb = *(const f32x4*)(wsrc + 4);
            float wv[8] = {wa[0], wa[1], wa[2], wa[3], wb[0], wb[1], wb[2], wb[3]};
            ushortx8 us;
#pragma unroll
            for (int j = 0; j < 8; ++j) us[j] = f2bf(wv[j]);   // RNE for weights
            *(ushortx8*)(&w2s[slot * 8]) = us;
        }
    }

    // stage ALL 32 ligand rows of b: 32 x 128 f32 = 1024 f32x4, 4 per thread
    // (stride 128 exact: reads below are wave-uniform per 16-lane group ->
    //  LDS broadcast, conflict-free regardless of stride)
    {
        const float* zlg = Z + (size_t)(b * NLB) * H1DIM;
#pragma unroll
        for (int s = 0; s < 4; ++s) {
            const int u   = tid + s * 256;                // 0..1023
            const int row = u >> 5;
            const int c4  = u & 31;
            f32x4 v = *(const f32x4*)(zlg + (size_t)row * H1DIM + c4 * 4);
            *(f32x4*)(&zl[row * H1DIM + c4 * 4]) = v;
        }
    }

    const int lane = tid & 63;
    const int widx = tid >> 6;
    const int c    = lane & 15;
    const int q    = lane >> 4;

    // pocket rows in registers: lane c holds Z row (NL_TOT + b*160 + jt*16 + c),
    // all 4 K-slices (32 VGPR). Same f32 bits the LDS zp tile held -> math
    // identical. Loaded once per block, L2-resident.
    f32x4 pk[4][2];
    {
        const float* pkg = Z + (size_t)(NL_TOT + b * NPB + jt * JT_CHUNK + c) * H1DIM;
#pragma unroll
        for (int ks = 0; ks < 4; ++ks) {
            const int k0 = ks * 32 + q * 8;
            pk[ks][0] = *(const f32x4*)(pkg + k0);
            pk[ks][1] = *(const f32x4*)(pkg + k0 + 4);
        }
    }

    float b2f[4], w3f[4];
#pragma unroll
    for (int nt = 0; nt < 4; ++nt) {
        b2f[nt] = b2[nt * 16 + c];
        w3f[nt] = W3[nt * 16 + c];
    }
    const float b3v = b3[0];

    __syncthreads();   // W2 + zl visible; the ONLY barrier

    const unsigned short* wbase = &w2s[lane * 8];          // + chunk*512 ushorts

#pragma unroll
    for (int g = 0; g < 4; ++g) {                  // atom groups of 8
        // b2 folded into acc init (saves epilogue adds)
        f32x4 acc0[4], acc1[4];
#pragma unroll
        for (int nt = 0; nt < 4; ++nt) {
            const float bb = b2f[nt];
            acc0[nt] = (f32x4){bb, bb, bb, bb};
            acc1[nt] = (f32x4){bb, bb, bb, bb};
        }

        // wave's atom pair for this group: i0 = g*8 + widx*2, i0+1
        const float* lrow0 = &zl[(g * 8 + widx * 2) * H1DIM];

#pragma unroll
        for (int ks = 0; ks < 4; ++ks) {           // K = 128 = 4 x 32
            const int k0 = ks * 32 + q * 8;
            bf16x8 bfr[4];
#pragma unroll
            for (int nt = 0; nt < 4; ++nt)         // conflict-free ds_read_b128
                bfr[nt] = *(const bf16x8*)(wbase + (nt * 4 + ks) * 512);
            const f32x4 pa = pk[ks][0];            // register pocket operands
            const f32x4 pb = pk[ks][1];
            // ligand operands from LDS (16-lane broadcast reads)
            f32x4 la0 = *(const f32x4*)(lrow0 + k0);
            f32x4 la1 = *(const f32x4*)(lrow0 + k0 + 4);
            f32x4 lb0 = *(const f32x4*)(lrow0 + H1DIM + k0);
            f32x4 lb1 = *(const f32x4*)(lrow0 + H1DIM + k0 + 4);
            float hv0[8], hv1[8];
#pragma unroll
            for (int j = 0; j < 4; ++j) {
                hv0[j]     = fast_silu(pa[j] + la0[j]);
                hv0[4 + j] = fast_silu(pb[j] + la1[j]);
                hv1[j]     = fast_silu(pa[j] + lb0[j]);
                hv1[4 + j] = fast_silu(pb[j] + lb1[j]);
            }
            bf16x8 a0f = pack8_rhu(hv0);
            bf16x8 a1f = pack8_rhu(hv1);
#pragma unroll
            for (int nt = 0; nt < 4; ++nt)         // 8 independent MFMAs
                acc0[nt] = __builtin_amdgcn_mfma_f32_16x16x32_bf16(a0f, bfr[nt], acc0[nt], 0, 0, 0);
#pragma unroll
            for (int nt = 0; nt < 4; ++nt)
                acc1[nt] = __builtin_amdgcn_mfma_f32_16x16x32_bf16(a1f, bfr[nt], acc1[nt], 0, 0, 0);
        }

        // epilogues (b2 already in acc): lane holds D[m=q*4+r][n=nt*16+c]
#pragma unroll
        for (int at = 0; at < 2; ++at) {
            const f32x4* A = at ? acc1 : acc0;
            float s0 = 0.f, s1 = 0.f, s2 = 0.f, s3 = 0.f;
#pragma unroll
            for (int nt = 0; nt < 4; ++nt) {
                s0 += fast_silu(A[nt][0]) * w3f[nt];
                s1 += fast_silu(A[nt][1]) * w3f[nt];
                s2 += fast_silu(A[nt][2]) * w3f[nt];
                s3 += fast_silu(A[nt][3]) * w3f[nt];
            }
            s0 = rowsum16(s0);
            s1 = rowsum16(s1);
            s2 = rowsum16(s2);
            s3 = rowsum16(s3);
            if (c < 4) {
                float v = (c == 0) ? s0 : (c == 1) ? s1 : (c == 2) ? s2 : s3;
                const int e0 = (b * NLB + g * 8 + widx * 2 + at) * NPB + jt * JT_CHUNK;
                out[e0 + q * 4 + c] = fmaxf(v + b3v, 0.0f);
            }
        }
    }
}

// ---------------------------------------------------------------------------
extern "C" void kernel_launch(void* const* d_in, const int* in_sizes, int n_in,
                              void* d_out, int out_size, void* d_ws, size_t ws_size,
                              hipStream_t stream)
{
    const float* s_lig = (const float*)d_in[0];
    const float* s_poc = (const float*)d_in[1];
    const float* W1    = (const float*)d_in[4];
    const float* b1    = (const float*)d_in[5];
    const float* W2    = (const float*)d_in[6];
    const float* b2    = (const float*)d_in[7];
    const float* W3    = (const float*)d_in[8];
    const float* b3    = (const float*)d_in[9];

    float* Z = (float*)d_ws;   // NROWS*H1DIM*4 = 12.58 MB workspace

    hipLaunchKernelGGL(proj_kernel, dim3(NROWS / 16 / 4 * 2), dim3(256), 0, stream,
                       s_lig, s_poc, W1, b1, Z);
    hipLaunchKernelGGL(edge_kernel, dim3(EDGE_BLOCKS), dim3(256), 0, stream,
                       Z, W2, b2, W3, b3, (float*)d_out);
}

// Round 8
// 135.617 us; speedup vs baseline: 1.0456x; 1.0456x over previous
//
#include <hip/hip_runtime.h>
#include <hip/hip_bf16.h>

// ---------------------------------------------------------------------------
// HiddenEdgeDistanceMLP on MI355X (gfx950)
//
// reference:  s = s_lig[l] + s_poc[p]          [E,256]
//             h1 = silu(s @ W1.T + b1)         [E,128]
//             h2 = silu(h1 @ W2.T + b2)        [E,64]
//             out = relu(h2 @ W3.T + b3)       [E]
//
// v20 (R7): INVENTORY CUT on the v18 structure (best: 47.4us edge).
//   R6 post-mortem: occupancy UP (24->30%) but 6us SLOWER -> latency-coverage
//   theory dead. Busy is invariant 33-35us across ALL R1-R6 structures ->
//   edge is VALU-issue-inventory bound. So: keep v18's memory layout
//   (zp+zl+w2s in LDS, 1280 (b,jt) blocks, 1 barrier) and cut ops:
//   (1) exp2 pre-scale (EXACT algebra): zl,zp staged x(-log2e), W2 staged
//       x(-ln2). silu becomes t=zl'+zp'; u = t*rcp(1+exp2(t)); and
//       u @ W2'.T == silu(s) @ W2.T since u = -log2e*silu(s). Removes the
//       hidden x(log2e) v_mul inside __expf per main-loop silu (64/g).
//   (2) pack8 RHU(12 ops) -> native RNE bf16 convertvector pairs
//       (v_cvt_pk_bf16_f32, 4-8 ops). C-level, no inline asm (m240).
//   ~17% issue-inventory cut. Numerics: h1 rounding RHU->RNE + scaled grid;
//   error magnitude unchanged (~2^-9 rel); threshold headroom 3.8x.
//   Epilogue/acc/b2/W3 path untouched (A arrives unscaled).
// v18 mechanisms kept: block=(b,jt) grid 1280, zl[32][128] + zp[16][132] +
//   w2s in LDS, zero barriers after the initial one, 2-atoms-per-K-pass,
//   b2 folded into acc init, DPP rowsum, no min-waves bound.
// ---------------------------------------------------------------------------

#define B_CPLX   128
#define NLB      32
#define NPB      160
#define SDIM     256
#define H1DIM    128
#define NL_TOT   (B_CPLX * NLB)         // 4096
#define NP_TOT   (B_CPLX * NPB)         // 20480
#define NROWS    (NL_TOT + NP_TOT)      // 24576
#define E_TOT    (B_CPLX * NLB * NPB)   // 655360

#define W1_LDS_STRIDE 264               // 256 + 8 bf16 pad
#define JT_CHUNK 16                     // pocket rows per block
#define ZP_STRIDE 132                   // 128 + 4 f32 pad (2-way banks, free)

#define EDGE_BLOCKS (B_CPLX * 10)       // 1280 = (b, jt)

#define NEG_LOG2E -1.4426950408889634f  // -log2(e): silu input pre-scale
#define NEG_LN2   -0.69314718055994531f // -ln(2):   W2 compensation

typedef __bf16 bf16x8 __attribute__((ext_vector_type(8)));
typedef __bf16 bf16x2 __attribute__((ext_vector_type(2)));
typedef unsigned short ushortx8 __attribute__((ext_vector_type(8)));
typedef unsigned short ushortx4 __attribute__((ext_vector_type(4)));
typedef unsigned uintx4 __attribute__((ext_vector_type(4)));
typedef float f32x4 __attribute__((ext_vector_type(4)));
typedef float f32x2 __attribute__((ext_vector_type(2)));

#if __has_builtin(__builtin_amdgcn_exp2f)
#define EXP2F(x) __builtin_amdgcn_exp2f(x)
#else
#define EXP2F(x) exp2f(x)
#endif

__device__ __forceinline__ unsigned short f2bf(float f) {
    unsigned u = __builtin_bit_cast(unsigned, f);
    u += 0x7FFFu + ((u >> 16) & 1u);          // round-to-nearest-even
    return (unsigned short)(u >> 16);
}

// v_perm_b32: pack hi16(x0) low, hi16(x1) high (1 op)
__device__ __forceinline__ unsigned perm_hi16u(unsigned u0, unsigned u1) {
    return __builtin_amdgcn_perm(u1, u0, 0x07060302u);
}

// round-half-up bf16 pair pack: bitpattern + 0x8000 then take hi16.
__device__ __forceinline__ unsigned pack2_rhu(float x0, float x1) {
    unsigned u0 = __builtin_bit_cast(unsigned, x0) + 0x8000u;
    unsigned u1 = __builtin_bit_cast(unsigned, x1) + 0x8000u;
    return perm_hi16u(u0, u1);
}

// RNE pack via HW v_cvt_pk_bf16_f32 (compiler-lowered, no inline asm)
__device__ __forceinline__ bf16x8 pack8_rne(const float* x) {
    bf16x8 r;
#pragma unroll
    for (int j = 0; j < 4; ++j) {
        f32x2 p = {x[2 * j], x[2 * j + 1]};
        bf16x2 b = __builtin_convertvector(p, bf16x2);
        r[2 * j]     = b[0];
        r[2 * j + 1] = b[1];
    }
    return r;
}

// hi/lo exact split (proj only): hi = trunc bf16, lo = bf16(x - hi)
__device__ __forceinline__ void pack_split(const float* x, bf16x8& hi, bf16x8& lo) {
    uintx4 h, l;
#pragma unroll
    for (int j = 0; j < 4; ++j) {
        float x0 = x[2 * j], x1 = x[2 * j + 1];
        unsigned u0 = __builtin_bit_cast(unsigned, x0);
        unsigned u1 = __builtin_bit_cast(unsigned, x1);
        h[j] = perm_hi16u(u0, u1);
        float hf0 = __builtin_bit_cast(float, u0 & 0xFFFF0000u);
        float hf1 = __builtin_bit_cast(float, u1 & 0xFFFF0000u);
        l[j] = pack2_rhu(x0 - hf0, x1 - hf1);
    }
    hi = __builtin_bit_cast(bf16x8, h);
    lo = __builtin_bit_cast(bf16x8, l);
}

__device__ __forceinline__ float fast_silu(float x) {
    return x * __builtin_amdgcn_rcpf(1.0f + __expf(-x));
}

// pre-scaled silu: t = -log2e * s  ->  u = t * sigma(s) = -log2e * silu(s)
// (exp2 direct: no hidden x(log2e) mul; compensation folded into W2')
__device__ __forceinline__ float silu_u(float t) {
    float e = EXP2F(t);
    float r = __builtin_amdgcn_rcpf(1.0f + e);
    return t * r;
}

// full-rate 16-lane row reduction: v_add_f32 + dpp row_ror 1,2,4,8
__device__ __forceinline__ float rowsum16(float s) {
    int b;
    b = __builtin_bit_cast(int, s);
    b = __builtin_amdgcn_update_dpp(b, b, 0x121, 0xF, 0xF, false);  // ror:1
    s += __builtin_bit_cast(float, b);
    b = __builtin_bit_cast(int, s);
    b = __builtin_amdgcn_update_dpp(b, b, 0x122, 0xF, 0xF, false);  // ror:2
    s += __builtin_bit_cast(float, b);
    b = __builtin_bit_cast(int, s);
    b = __builtin_amdgcn_update_dpp(b, b, 0x124, 0xF, 0xF, false);  // ror:4
    s += __builtin_bit_cast(float, b);
    b = __builtin_bit_cast(int, s);
    b = __builtin_amdgcn_update_dpp(b, b, 0x128, 0xF, 0xF, false);  // ror:8
    s += __builtin_bit_cast(float, b);
    return s;
}

// ---------------------------------------------------------------------------
// Kernel 1: Z[m][n] = X[m] @ W1[n] (+ b1[n] if m is a ligand row)
//   768 blocks = 384 row-tile groups x 2 N-halves; hi/lo split -> Z ~exact.
//   (verbatim v12)
// ---------------------------------------------------------------------------
__global__ __launch_bounds__(256) void proj_kernel(
    const float* __restrict__ s_lig, const float* __restrict__ s_poc,
    const float* __restrict__ W1,    const float* __restrict__ b1,
    float* __restrict__ Z)
{
    __shared__ unsigned short w1s[64 * W1_LDS_STRIDE];   // 33.8 KB

    const int tid  = threadIdx.x;
    const int tg   = blockIdx.x >> 1;             // row-tile group 0..383
    const int half = blockIdx.x & 1;              // N half

    {
        const f32x4* w4 = (const f32x4*)(W1 + (size_t)half * 64 * SDIM);  // 4096 units
#pragma unroll
        for (int r = 0; r < 2; ++r) {
            f32x4 t[8];
#pragma unroll
            for (int s = 0; s < 8; ++s) t[s] = w4[tid + (r * 8 + s) * 256];
#pragma unroll
            for (int s = 0; s < 8; ++s) {
                const int u = tid + (r * 8 + s) * 256;
                const int n = u >> 6;             // 64 f32x4 per 256-col row
                const int k4 = u & 63;
                ushortx4 us;
#pragma unroll
                for (int j = 0; j < 4; ++j) us[j] = f2bf(t[s][j]);
                *(ushortx4*)(&w1s[n * W1_LDS_STRIDE + k4 * 4]) = us;
            }
        }
    }
    __syncthreads();

    const int lane = tid & 63;
    const int widx = tid >> 6;
    const int c    = lane & 15;
    const int q    = lane >> 4;
    const int tile = tg * 4 + widx;               // 0..1535
    const int row  = tile * 16 + c;

    const float* src = (row < NL_TOT) ? (s_lig + (size_t)row * SDIM)
                                      : (s_poc + (size_t)(row - NL_TOT) * SDIM);

    f32x4 acc[4];
#pragma unroll
    for (int nt = 0; nt < 4; ++nt) acc[nt] = (f32x4){0.f, 0.f, 0.f, 0.f};

#pragma unroll
    for (int ks = 0; ks < 8; ++ks) {              // K = 256 = 8 x 32
        const int k0 = ks * 32 + q * 8;
        f32x4 xa = *reinterpret_cast<const f32x4*>(src + k0);
        f32x4 xb = *reinterpret_cast<const f32x4*>(src + k0 + 4);
        float xv[8] = {xa[0], xa[1], xa[2], xa[3], xb[0], xb[1], xb[2], xb[3]};
        bf16x8 ahi, alo;
        pack_split(xv, ahi, alo);
        bf16x8 bfrag[4];
#pragma unroll
        for (int nt = 0; nt < 4; ++nt)
            bfrag[nt] = *reinterpret_cast<const bf16x8*>(
                &w1s[(nt * 16 + c) * W1_LDS_STRIDE + k0]);
#pragma unroll
        for (int nt = 0; nt < 4; ++nt)            // hi pass (dep distance 4)
            acc[nt] = __builtin_amdgcn_mfma_f32_16x16x32_bf16(ahi, bfrag[nt], acc[nt], 0, 0, 0);
#pragma unroll
        for (int nt = 0; nt < 4; ++nt)            // lo pass
            acc[nt] = __builtin_amdgcn_mfma_f32_16x16x32_bf16(alo, bfrag[nt], acc[nt], 0, 0, 0);
    }

    // C/D layout: col n' = lane&15, row m = q*4 + reg
    const int mb = tile * 16 + q * 4;
#pragma unroll
    for (int nt = 0; nt < 4; ++nt) {
        const int n = half * 64 + nt * 16 + c;
        const float bias = b1[n];
#pragma unroll
        for (int r = 0; r < 4; ++r) {
            const int m = mb + r;
            float v = acc[nt][r];
            if (m < NL_TOT) v += bias;            // fold b1 into ligand rows only
            Z[(size_t)m * H1DIM + n] = v;
        }
    }
}

// ---------------------------------------------------------------------------
// Kernel 2: block = (complex b, pocket chunk jt); 1280 blocks x 4 waves.
//   v18 memory structure; zl/zp staged PRE-SCALED by -log2e, W2 staged
//   PRE-SCALED by -ln2 (exp2 trick). ZERO barriers after the initial one.
// ---------------------------------------------------------------------------
__global__ __launch_bounds__(256) void edge_kernel(
    const float* __restrict__ Z,
    const float* __restrict__ W2, const float* __restrict__ b2,
    const float* __restrict__ W3, const float* __restrict__ b3,
    float* __restrict__ out)
{
    __shared__ float zp[JT_CHUNK * ZP_STRIDE];            // 8.4 KB (scaled)
    __shared__ float zl[NLB * H1DIM];                     // 16 KB (scaled)
    __shared__ unsigned short w2s[16 * 64 * 8];           // 16 KB frag-ordered

    const int tid = threadIdx.x;
    const int b   = blockIdx.x / 10;
    const int jt  = blockIdx.x - b * 10;          // 0..9

    // stage W2' = W2 * (-ln2) as bf16 B-fragments, fragment-ordered:
    //   slot = chunk*64 + lane, chunk = nt*4 + ks;
    //   frag(lane) = W2'[n = nt*16 + (lane&15)][ks*32 + (lane>>4)*8 .. +8]
    {
#pragma unroll
        for (int s = 0; s < 4; ++s) {
            const int slot   = tid + s * 256;             // 0..1023
            const int lane_s = slot & 63;
            const int chunk  = slot >> 6;
            const int nt     = chunk >> 2;
            const int ks     = chunk & 3;
            const int n      = nt * 16 + (lane_s & 15);
            const int k0     = ks * 32 + (lane_s >> 4) * 8;
            const float* wsrc = W2 + (size_t)n * H1DIM + k0;
            f32x4 wa = *(const f32x4*)wsrc;
            f32x4 wb = *(const f32x4*)(wsrc + 4);
            float wv[8] = {wa[0], wa[1], wa[2], wa[3], wb[0], wb[1], wb[2], wb[3]};
            ushortx8 us;
#pragma unroll
            for (int j = 0; j < 8; ++j) us[j] = f2bf(wv[j] * NEG_LN2);
            *(ushortx8*)(&w2s[slot * 8]) = us;
        }
    }

    // stage pocket rows x(-log2e): 16 rows x 128 f32 = 512 f32x4, 2/thread
    {
        const float* zpg = Z + (size_t)(NL_TOT + b * NPB + jt * JT_CHUNK) * H1DIM;
#pragma unroll
        for (int s = 0; s < 2; ++s) {
            const int u   = tid + s * 256;
            const int row = u >> 5;
            const int c4  = u & 31;
            f32x4 v = *(const f32x4*)(zpg + (size_t)row * H1DIM + c4 * 4);
            v *= NEG_LOG2E;
            *(f32x4*)(&zp[row * ZP_STRIDE + c4 * 4]) = v;
        }
    }

    // stage ALL 32 ligand rows of b x(-log2e): 1024 f32x4, 4/thread
    {
        const float* zlg = Z + (size_t)(b * NLB) * H1DIM;
#pragma unroll
        for (int s = 0; s < 4; ++s) {
            const int u   = tid + s * 256;                // 0..1023
            const int row = u >> 5;
            const int c4  = u & 31;
            f32x4 v = *(const f32x4*)(zlg + (size_t)row * H1DIM + c4 * 4);
            v *= NEG_LOG2E;
            *(f32x4*)(&zl[row * H1DIM + c4 * 4]) = v;
        }
    }

    const int lane = tid & 63;
    const int widx = tid >> 6;
    const int c    = lane & 15;
    const int q    = lane >> 4;

    float b2f[4], w3f[4];
#pragma unroll
    for (int nt = 0; nt < 4; ++nt) {
        b2f[nt] = b2[nt * 16 + c];
        w3f[nt] = W3[nt * 16 + c];
    }
    const float b3v = b3[0];

    __syncthreads();   // W2 + zp + zl visible; the ONLY barrier

    const float* prow = &zp[c * ZP_STRIDE];
    const unsigned short* wbase = &w2s[lane * 8];          // + chunk*512 ushorts

#pragma unroll
    for (int g = 0; g < 4; ++g) {                  // atom groups of 8
        // b2 folded into acc init (saves epilogue adds)
        f32x4 acc0[4], acc1[4];
#pragma unroll
        for (int nt = 0; nt < 4; ++nt) {
            const float bb = b2f[nt];
            acc0[nt] = (f32x4){bb, bb, bb, bb};
            acc1[nt] = (f32x4){bb, bb, bb, bb};
        }

        // wave's atom pair for this group: i0 = g*8 + widx*2, i0+1
        const float* lrow0 = &zl[(g * 8 + widx * 2) * H1DIM];

#pragma unroll
        for (int ks = 0; ks < 4; ++ks) {           // K = 128 = 4 x 32
            const int k0 = ks * 32 + q * 8;
            bf16x8 bfr[4];
#pragma unroll
            for (int nt = 0; nt < 4; ++nt)         // conflict-free ds_read_b128
                bfr[nt] = *(const bf16x8*)(wbase + (nt * 4 + ks) * 512);
            f32x4 pa = *(const f32x4*)(prow + k0);
            f32x4 pb = *(const f32x4*)(prow + k0 + 4);
            // ligand operands from LDS (16-lane broadcast reads)
            f32x4 la0 = *(const f32x4*)(lrow0 + k0);
            f32x4 la1 = *(const f32x4*)(lrow0 + k0 + 4);
            f32x4 lb0 = *(const f32x4*)(lrow0 + H1DIM + k0);
            f32x4 lb1 = *(const f32x4*)(lrow0 + H1DIM + k0 + 4);
            float hv0[8], hv1[8];
#pragma unroll
            for (int j = 0; j < 4; ++j) {          // u = -log2e * silu(s)
                hv0[j]     = silu_u(pa[j] + la0[j]);
                hv0[4 + j] = silu_u(pb[j] + la1[j]);
                hv1[j]     = silu_u(pa[j] + lb0[j]);
                hv1[4 + j] = silu_u(pb[j] + lb1[j]);
            }
            bf16x8 a0f = pack8_rne(hv0);
            bf16x8 a1f = pack8_rne(hv1);
#pragma unroll
            for (int nt = 0; nt < 4; ++nt)         // 8 independent MFMAs
                acc0[nt] = __builtin_amdgcn_mfma_f32_16x16x32_bf16(a0f, bfr[nt], acc0[nt], 0, 0, 0);
#pragma unroll
            for (int nt = 0; nt < 4; ++nt)
                acc1[nt] = __builtin_amdgcn_mfma_f32_16x16x32_bf16(a1f, bfr[nt], acc1[nt], 0, 0, 0);
        }

        // epilogues (b2 already in acc; acc is true h2 pre-activation):
        // lane holds D[m=q*4+r][n=nt*16+c]
#pragma unroll
        for (int at = 0; at < 2; ++at) {
            const f32x4* A = at ? acc1 : acc0;
            float s0 = 0.f, s1 = 0.f, s2 = 0.f, s3 = 0.f;
#pragma unroll
            for (int nt = 0; nt < 4; ++nt) {
                s0 += fast_silu(A[nt][0]) * w3f[nt];
                s1 += fast_silu(A[nt][1]) * w3f[nt];
                s2 += fast_silu(A[nt][2]) * w3f[nt];
                s3 += fast_silu(A[nt][3]) * w3f[nt];
            }
            s0 = rowsum16(s0);
            s1 = rowsum16(s1);
            s2 = rowsum16(s2);
            s3 = rowsum16(s3);
            if (c < 4) {
                float v = (c == 0) ? s0 : (c == 1) ? s1 : (c == 2) ? s2 : s3;
                const int e0 = (b * NLB + g * 8 + widx * 2 + at) * NPB + jt * JT_CHUNK;
                out[e0 + q * 4 + c] = fmaxf(v + b3v, 0.0f);
            }
        }
    }
}

// ---------------------------------------------------------------------------
extern "C" void kernel_launch(void* const* d_in, const int* in_sizes, int n_in,
                              void* d_out, int out_size, void* d_ws, size_t ws_size,
                              hipStream_t stream)
{
    const float* s_lig = (const float*)d_in[0];
    const float* s_poc = (const float*)d_in[1];
    const float* W1    = (const float*)d_in[4];
    const float* b1    = (const float*)d_in[5];
    const float* W2    = (const float*)d_in[6];
    const float* b2    = (const float*)d_in[7];
    const float* W3    = (const float*)d_in[8];
    const float* b3    = (const float*)d_in[9];

    float* Z = (float*)d_ws;   // NROWS*H1DIM*4 = 12.58 MB workspace

    hipLaunchKernelGGL(proj_kernel, dim3(NROWS / 16 / 4 * 2), dim3(256), 0, stream,
                       s_lig, s_poc, W1, b1, Z);
    hipLaunchKernelGGL(edge_kernel, dim3(EDGE_BLOCKS), dim3(256), 0, stream,
                       Z, W2, b2, W3, b3, (float*)d_out);
}

// Round 9
// 131.450 us; speedup vs baseline: 1.0788x; 1.0317x over previous
//
#include <hip/hip_runtime.h>
#include <hip/hip_bf16.h>

// ---------------------------------------------------------------------------
// HiddenEdgeDistanceMLP on MI355X (gfx950)
//
// reference:  s = s_lig[l] + s_poc[p]          [E,256]
//             h1 = silu(s @ W1.T + b1)         [E,128]
//             h2 = silu(h1 @ W2.T + b2)        [E,64]
//             out = relu(h2 @ W3.T + b3)       [E]
//
// v21 (R8): MORE INVENTORY CUTS on the v20 structure (44.0us edge, R7
//   confirmed edge time ~ VALU issue inventory).
//   (1) Epilogue exp2 trick (EXACT algebra, completes R7's transform):
//       W2 staged UNSCALED (plain RNE bf16; also deletes the staging mul),
//       acc init = -log2e*b2  ->  acc_final = -log2e*h2pre = t2;
//       epilogue u2 = t2*rcp(1+exp2(t2)) = -log2e*silu(h2pre);
//       w3f pre-scaled by -ln2  ->  u2 . w3f' = silu(h2) @ W3.  No hidden
//       x(log2e) mul in the 128 epilogue silus/wave.
//   (2) 4 atoms per K-pass (2 h-iters x 4 atoms, was 4 g x 2): the same
//       4 W2-frag + 2 pocket ds_reads per ks feed 4 atoms -> per-wave
//       ds_reads 160->112, loop overhead halves. Per-edge math, MFMA count,
//       epilogue untouched (pure scheduling; R3's failure was pk-f32, not
//       scheduling — R4 proved it).
//   No pk-f32 anywhere. absmax expected ~0.00195 (PASS).
// v20/v18 mechanisms kept: block=(b,jt) grid 1280, zp+zl+w2s in LDS, one
//   barrier total, exp2 pre-scale main loop (zl/zp staged x -log2e),
//   RNE cvt_pk pack, b2 folded into acc init, DPP rowsum, no min-waves.
// ---------------------------------------------------------------------------

#define B_CPLX   128
#define NLB      32
#define NPB      160
#define SDIM     256
#define H1DIM    128
#define NL_TOT   (B_CPLX * NLB)         // 4096
#define NP_TOT   (B_CPLX * NPB)         // 20480
#define NROWS    (NL_TOT + NP_TOT)      // 24576
#define E_TOT    (B_CPLX * NLB * NPB)   // 655360

#define W1_LDS_STRIDE 264               // 256 + 8 bf16 pad
#define JT_CHUNK 16                     // pocket rows per block
#define ZP_STRIDE 132                   // 128 + 4 f32 pad (bank spread)

#define EDGE_BLOCKS (B_CPLX * 10)       // 1280 = (b, jt)

#define NEG_LOG2E -1.4426950408889634f  // -log2(e)
#define NEG_LN2   -0.69314718055994531f // -ln(2)

typedef __bf16 bf16x8 __attribute__((ext_vector_type(8)));
typedef __bf16 bf16x2 __attribute__((ext_vector_type(2)));
typedef unsigned short ushortx8 __attribute__((ext_vector_type(8)));
typedef unsigned short ushortx4 __attribute__((ext_vector_type(4)));
typedef unsigned uintx4 __attribute__((ext_vector_type(4)));
typedef float f32x4 __attribute__((ext_vector_type(4)));
typedef float f32x2 __attribute__((ext_vector_type(2)));

#if __has_builtin(__builtin_amdgcn_exp2f)
#define EXP2F(x) __builtin_amdgcn_exp2f(x)
#else
#define EXP2F(x) exp2f(x)
#endif

__device__ __forceinline__ unsigned short f2bf(float f) {
    unsigned u = __builtin_bit_cast(unsigned, f);
    u += 0x7FFFu + ((u >> 16) & 1u);          // round-to-nearest-even
    return (unsigned short)(u >> 16);
}

// v_perm_b32: pack hi16(x0) low, hi16(x1) high (1 op)
__device__ __forceinline__ unsigned perm_hi16u(unsigned u0, unsigned u1) {
    return __builtin_amdgcn_perm(u1, u0, 0x07060302u);
}

// round-half-up bf16 pair pack: bitpattern + 0x8000 then take hi16.
__device__ __forceinline__ unsigned pack2_rhu(float x0, float x1) {
    unsigned u0 = __builtin_bit_cast(unsigned, x0) + 0x8000u;
    unsigned u1 = __builtin_bit_cast(unsigned, x1) + 0x8000u;
    return perm_hi16u(u0, u1);
}

// RNE pack via HW v_cvt_pk_bf16_f32 (compiler-lowered, no inline asm)
__device__ __forceinline__ bf16x8 pack8_rne(const float* x) {
    bf16x8 r;
#pragma unroll
    for (int j = 0; j < 4; ++j) {
        f32x2 p = {x[2 * j], x[2 * j + 1]};
        bf16x2 b = __builtin_convertvector(p, bf16x2);
        r[2 * j]     = b[0];
        r[2 * j + 1] = b[1];
    }
    return r;
}

// hi/lo exact split (proj only): hi = trunc bf16, lo = bf16(x - hi)
__device__ __forceinline__ void pack_split(const float* x, bf16x8& hi, bf16x8& lo) {
    uintx4 h, l;
#pragma unroll
    for (int j = 0; j < 4; ++j) {
        float x0 = x[2 * j], x1 = x[2 * j + 1];
        unsigned u0 = __builtin_bit_cast(unsigned, x0);
        unsigned u1 = __builtin_bit_cast(unsigned, x1);
        h[j] = perm_hi16u(u0, u1);
        float hf0 = __builtin_bit_cast(float, u0 & 0xFFFF0000u);
        float hf1 = __builtin_bit_cast(float, u1 & 0xFFFF0000u);
        l[j] = pack2_rhu(x0 - hf0, x1 - hf1);
    }
    hi = __builtin_bit_cast(bf16x8, h);
    lo = __builtin_bit_cast(bf16x8, l);
}

// pre-scaled silu: t = -log2e * s  ->  u = t * sigma(s) = -log2e * silu(s)
__device__ __forceinline__ float silu_u(float t) {
    float e = EXP2F(t);
    float r = __builtin_amdgcn_rcpf(1.0f + e);
    return t * r;
}

// full-rate 16-lane row reduction: v_add_f32 + dpp row_ror 1,2,4,8
__device__ __forceinline__ float rowsum16(float s) {
    int b;
    b = __builtin_bit_cast(int, s);
    b = __builtin_amdgcn_update_dpp(b, b, 0x121, 0xF, 0xF, false);  // ror:1
    s += __builtin_bit_cast(float, b);
    b = __builtin_bit_cast(int, s);
    b = __builtin_amdgcn_update_dpp(b, b, 0x122, 0xF, 0xF, false);  // ror:2
    s += __builtin_bit_cast(float, b);
    b = __builtin_bit_cast(int, s);
    b = __builtin_amdgcn_update_dpp(b, b, 0x124, 0xF, 0xF, false);  // ror:4
    s += __builtin_bit_cast(float, b);
    b = __builtin_bit_cast(int, s);
    b = __builtin_amdgcn_update_dpp(b, b, 0x128, 0xF, 0xF, false);  // ror:8
    s += __builtin_bit_cast(float, b);
    return s;
}

// ---------------------------------------------------------------------------
// Kernel 1: Z[m][n] = X[m] @ W1[n] (+ b1[n] if m is a ligand row)
//   768 blocks = 384 row-tile groups x 2 N-halves; hi/lo split -> Z ~exact.
//   (verbatim v12)
// ---------------------------------------------------------------------------
__global__ __launch_bounds__(256) void proj_kernel(
    const float* __restrict__ s_lig, const float* __restrict__ s_poc,
    const float* __restrict__ W1,    const float* __restrict__ b1,
    float* __restrict__ Z)
{
    __shared__ unsigned short w1s[64 * W1_LDS_STRIDE];   // 33.8 KB

    const int tid  = threadIdx.x;
    const int tg   = blockIdx.x >> 1;             // row-tile group 0..383
    const int half = blockIdx.x & 1;              // N half

    {
        const f32x4* w4 = (const f32x4*)(W1 + (size_t)half * 64 * SDIM);  // 4096 units
#pragma unroll
        for (int r = 0; r < 2; ++r) {
            f32x4 t[8];
#pragma unroll
            for (int s = 0; s < 8; ++s) t[s] = w4[tid + (r * 8 + s) * 256];
#pragma unroll
            for (int s = 0; s < 8; ++s) {
                const int u = tid + (r * 8 + s) * 256;
                const int n = u >> 6;             // 64 f32x4 per 256-col row
                const int k4 = u & 63;
                ushortx4 us;
#pragma unroll
                for (int j = 0; j < 4; ++j) us[j] = f2bf(t[s][j]);
                *(ushortx4*)(&w1s[n * W1_LDS_STRIDE + k4 * 4]) = us;
            }
        }
    }
    __syncthreads();

    const int lane = tid & 63;
    const int widx = tid >> 6;
    const int c    = lane & 15;
    const int q    = lane >> 4;
    const int tile = tg * 4 + widx;               // 0..1535
    const int row  = tile * 16 + c;

    const float* src = (row < NL_TOT) ? (s_lig + (size_t)row * SDIM)
                                      : (s_poc + (size_t)(row - NL_TOT) * SDIM);

    f32x4 acc[4];
#pragma unroll
    for (int nt = 0; nt < 4; ++nt) acc[nt] = (f32x4){0.f, 0.f, 0.f, 0.f};

#pragma unroll
    for (int ks = 0; ks < 8; ++ks) {              // K = 256 = 8 x 32
        const int k0 = ks * 32 + q * 8;
        f32x4 xa = *reinterpret_cast<const f32x4*>(src + k0);
        f32x4 xb = *reinterpret_cast<const f32x4*>(src + k0 + 4);
        float xv[8] = {xa[0], xa[1], xa[2], xa[3], xb[0], xb[1], xb[2], xb[3]};
        bf16x8 ahi, alo;
        pack_split(xv, ahi, alo);
        bf16x8 bfrag[4];
#pragma unroll
        for (int nt = 0; nt < 4; ++nt)
            bfrag[nt] = *reinterpret_cast<const bf16x8*>(
                &w1s[(nt * 16 + c) * W1_LDS_STRIDE + k0]);
#pragma unroll
        for (int nt = 0; nt < 4; ++nt)            // hi pass (dep distance 4)
            acc[nt] = __builtin_amdgcn_mfma_f32_16x16x32_bf16(ahi, bfrag[nt], acc[nt], 0, 0, 0);
#pragma unroll
        for (int nt = 0; nt < 4; ++nt)            // lo pass
            acc[nt] = __builtin_amdgcn_mfma_f32_16x16x32_bf16(alo, bfrag[nt], acc[nt], 0, 0, 0);
    }

    // C/D layout: col n' = lane&15, row m = q*4 + reg
    const int mb = tile * 16 + q * 4;
#pragma unroll
    for (int nt = 0; nt < 4; ++nt) {
        const int n = half * 64 + nt * 16 + c;
        const float bias = b1[n];
#pragma unroll
        for (int r = 0; r < 4; ++r) {
            const int m = mb + r;
            float v = acc[nt][r];
            if (m < NL_TOT) v += bias;            // fold b1 into ligand rows only
            Z[(size_t)m * H1DIM + n] = v;
        }
    }
}

// ---------------------------------------------------------------------------
// Kernel 2: block = (complex b, pocket chunk jt); 1280 blocks x 4 waves.
//   2 h-iterations x 4 atoms per wave (atoms h*16 + widx*4 + 0..3).
//   zl/zp staged x(-log2e); W2 staged UNSCALED; acc init -log2e*b2;
//   w3f x(-ln2). ZERO barriers after the initial one.
// ---------------------------------------------------------------------------
__global__ __launch_bounds__(256) void edge_kernel(
    const float* __restrict__ Z,
    const float* __restrict__ W2, const float* __restrict__ b2,
    const float* __restrict__ W3, const float* __restrict__ b3,
    float* __restrict__ out)
{
    __shared__ float zp[JT_CHUNK * ZP_STRIDE];            // 8.4 KB (scaled)
    __shared__ float zl[NLB * H1DIM];                     // 16 KB (scaled)
    __shared__ unsigned short w2s[16 * 64 * 8];           // 16 KB frag-ordered

    const int tid = threadIdx.x;
    const int b   = blockIdx.x / 10;
    const int jt  = blockIdx.x - b * 10;          // 0..9

    // stage W2 (UNSCALED, RNE bf16) as B-fragments, fragment-ordered:
    //   slot = chunk*64 + lane, chunk = nt*4 + ks;
    //   frag(lane) = W2[n = nt*16 + (lane&15)][ks*32 + (lane>>4)*8 .. +8]
    {
#pragma unroll
        for (int s = 0; s < 4; ++s) {
            const int slot   = tid + s * 256;             // 0..1023
            const int lane_s = slot & 63;
            const int chunk  = slot >> 6;
            const int nt     = chunk >> 2;
            const int ks     = chunk & 3;
            const int n      = nt * 16 + (lane_s & 15);
            const int k0     = ks * 32 + (lane_s >> 4) * 8;
            const float* wsrc = W2 + (size_t)n * H1DIM + k0;
            f32x4 wa = *(const f32x4*)wsrc;
            f32x4 wb = *(const f32x4*)(wsrc + 4);
            ushortx8 us;
#pragma unroll
            for (int j = 0; j < 4; ++j) {
                us[j]     = f2bf(wa[j]);
                us[4 + j] = f2bf(wb[j]);
            }
            *(ushortx8*)(&w2s[slot * 8]) = us;
        }
    }

    // stage pocket rows x(-log2e): 16 rows x 128 f32 = 512 f32x4, 2/thread
    {
        const float* zpg = Z + (size_t)(NL_TOT + b * NPB + jt * JT_CHUNK) * H1DIM;
#pragma unroll
        for (int s = 0; s < 2; ++s) {
            const int u   = tid + s * 256;
            const int row = u >> 5;
            const int c4  = u & 31;
            f32x4 v = *(const f32x4*)(zpg + (size_t)row * H1DIM + c4 * 4);
            v *= NEG_LOG2E;
            *(f32x4*)(&zp[row * ZP_STRIDE + c4 * 4]) = v;
        }
    }

    // stage ALL 32 ligand rows of b x(-log2e): 1024 f32x4, 4/thread
    {
        const float* zlg = Z + (size_t)(b * NLB) * H1DIM;
#pragma unroll
        for (int s = 0; s < 4; ++s) {
            const int u   = tid + s * 256;                // 0..1023
            const int row = u >> 5;
            const int c4  = u & 31;
            f32x4 v = *(const f32x4*)(zlg + (size_t)row * H1DIM + c4 * 4);
            v *= NEG_LOG2E;
            *(f32x4*)(&zl[row * H1DIM + c4 * 4]) = v;
        }
    }

    const int lane = tid & 63;
    const int widx = tid >> 6;
    const int c    = lane & 15;
    const int q    = lane >> 4;

    float b2f[4], w3f[4];
#pragma unroll
    for (int nt = 0; nt < 4; ++nt) {
        b2f[nt] = b2[nt * 16 + c] * NEG_LOG2E;    // acc accumulates t2 = -log2e*h2pre
        w3f[nt] = W3[nt * 16 + c] * NEG_LN2;      // u2 . w3f == silu(h2) @ W3
    }
    const float b3v = b3[0];

    __syncthreads();   // W2 + zp + zl visible; the ONLY barrier

    const float* prow = &zp[c * ZP_STRIDE];
    const unsigned short* wbase = &w2s[lane * 8];          // + chunk*512 ushorts

#pragma unroll
    for (int h = 0; h < 2; ++h) {                  // atom groups of 16
        // acc init = -log2e * b2 (epilogue exp2 trick)
        f32x4 acc[4][4];                           // [atom][nt]
#pragma unroll
        for (int a = 0; a < 4; ++a)
#pragma unroll
            for (int nt = 0; nt < 4; ++nt) {
                const float bb = b2f[nt];
                acc[a][nt] = (f32x4){bb, bb, bb, bb};
            }

        // wave's 4 atoms this group: h*16 + widx*4 + a
        const float* lrow0 = &zl[(h * 16 + widx * 4) * H1DIM];

#pragma unroll
        for (int ks = 0; ks < 4; ++ks) {           // K = 128 = 4 x 32
            const int k0 = ks * 32 + q * 8;
            bf16x8 bfr[4];
#pragma unroll
            for (int nt = 0; nt < 4; ++nt)         // conflict-free ds_read_b128
                bfr[nt] = *(const bf16x8*)(wbase + (nt * 4 + ks) * 512);
            f32x4 pa = *(const f32x4*)(prow + k0);
            f32x4 pb = *(const f32x4*)(prow + k0 + 4);
#pragma unroll
            for (int a = 0; a < 4; ++a) {          // 4 atoms share bfr/pa/pb
                // ligand operands from LDS (wave-uniform broadcast reads)
                f32x4 la0 = *(const f32x4*)(lrow0 + a * H1DIM + k0);
                f32x4 la1 = *(const f32x4*)(lrow0 + a * H1DIM + k0 + 4);
                float hv[8];
#pragma unroll
                for (int j = 0; j < 4; ++j) {      // u = -log2e * silu(s)
                    hv[j]     = silu_u(pa[j] + la0[j]);
                    hv[4 + j] = silu_u(pb[j] + la1[j]);
                }
                bf16x8 af = pack8_rne(hv);
#pragma unroll
                for (int nt = 0; nt < 4; ++nt)
                    acc[a][nt] = __builtin_amdgcn_mfma_f32_16x16x32_bf16(af, bfr[nt], acc[a][nt], 0, 0, 0);
            }
        }

        // epilogues: acc holds t2 = -log2e*h2pre; lane has D[m=q*4+r][n=nt*16+c]
#pragma unroll
        for (int at = 0; at < 4; ++at) {
            const f32x4* A = acc[at];
            float s0 = 0.f, s1 = 0.f, s2 = 0.f, s3 = 0.f;
#pragma unroll
            for (int nt = 0; nt < 4; ++nt) {       // u2 = -log2e*silu(h2pre)
                s0 += silu_u(A[nt][0]) * w3f[nt];
                s1 += silu_u(A[nt][1]) * w3f[nt];
                s2 += silu_u(A[nt][2]) * w3f[nt];
                s3 += silu_u(A[nt][3]) * w3f[nt];
            }
            s0 = rowsum16(s0);
            s1 = rowsum16(s1);
            s2 = rowsum16(s2);
            s3 = rowsum16(s3);
            if (c < 4) {
                float v = (c == 0) ? s0 : (c == 1) ? s1 : (c == 2) ? s2 : s3;
                const int e0 = (b * NLB + h * 16 + widx * 4 + at) * NPB + jt * JT_CHUNK;
                out[e0 + q * 4 + c] = fmaxf(v + b3v, 0.0f);
            }
        }
    }
}

// ---------------------------------------------------------------------------
extern "C" void kernel_launch(void* const* d_in, const int* in_sizes, int n_in,
                              void* d_out, int out_size, void* d_ws, size_t ws_size,
                              hipStream_t stream)
{
    const float* s_lig = (const float*)d_in[0];
    const float* s_poc = (const float*)d_in[1];
    const float* W1    = (const float*)d_in[4];
    const float* b1    = (const float*)d_in[5];
    const float* W2    = (const float*)d_in[6];
    const float* b2    = (const float*)d_in[7];
    const float* W3    = (const float*)d_in[8];
    const float* b3    = (const float*)d_in[9];

    float* Z = (float*)d_ws;   // NROWS*H1DIM*4 = 12.58 MB workspace

    hipLaunchKernelGGL(proj_kernel, dim3(NROWS / 16 / 4 * 2), dim3(256), 0, stream,
                       s_lig, s_poc, W1, b1, Z);
    hipLaunchKernelGGL(edge_kernel, dim3(EDGE_BLOCKS), dim3(256), 0, stream,
                       Z, W2, b2, W3, b3, (float*)d_out);
}

// Round 10
// 130.343 us; speedup vs baseline: 1.0879x; 1.0085x over previous
//
#include <hip/hip_runtime.h>
#include <hip/hip_bf16.h>

// ---------------------------------------------------------------------------
// HiddenEdgeDistanceMLP on MI355X (gfx950)
//
// reference:  s = s_lig[l] + s_poc[p]          [E,256]
//             h1 = silu(s @ W1.T + b1)         [E,128]
//             h2 = silu(h1 @ W2.T + b2)        [E,64]
//             out = relu(h2 @ W3.T + b3)       [E]
//
// v22 (R9): three inventory cuts on the v21 structure (edge ~40us, R7/R8
//   both matched the inventory model; trans floor ~12.8us is fixed):
//   (1) Z PRE-SCALED: proj stages W1 x(-log2e) before f2bf (free) and
//       scales b1 -> Z = -log2e*(X@W1+b1). Edge zl/zp staging becomes a
//       pure copy (x-log2e muls deleted).
//   (2) W2 PRE-CONVERTED: proj block 0 writes the fragment-ordered bf16 W2
//       (bitwise the v21 values) to ws after Z; edge stages it with plain
//       16B copies -> 1280 blocks' f2bf conversion deleted. No extra
//       kernel launch.
//   (3) SWAPPED-OPERAND h2 MFMA: mfma(bfr, af, acc) gives D^T BITWISE
//       (same products, same HW k-accumulation). Lane now holds h2
//       channels m=nt*16+q*4+r for pocket c -> W3 dot = 16 fma + 3 adds +
//       2 shfl_xor instead of 4x rowsum16 (32 DPP ops); b2/W3 load as
//       aligned f32x4; stores are 64B contiguous (lanes 0-15). Only the
//       final f32 dot is reassociated (irrelevant vs 2e-3 bf16 noise).
//   absmax: rounding realization changes (W1 rounded post-scale) ->
//   expect ~0.002, PASS (threshold 7.5e-3).
// v21 mechanisms kept: block=(b,jt) grid 1280, zp+zl+w2s in LDS, one
//   barrier, exp2 pre-scale main loop AND epilogue (w3 x -ln2, b2 x -log2e),
//   RNE cvt_pk pack, 2 h-iters x 4 atoms, DPP... (rowsum16 now gone).
// ---------------------------------------------------------------------------

#define B_CPLX   128
#define NLB      32
#define NPB      160
#define SDIM     256
#define H1DIM    128
#define NL_TOT   (B_CPLX * NLB)         // 4096
#define NP_TOT   (B_CPLX * NPB)         // 20480
#define NROWS    (NL_TOT + NP_TOT)      // 24576
#define E_TOT    (B_CPLX * NLB * NPB)   // 655360

#define W1_LDS_STRIDE 264               // 256 + 8 bf16 pad
#define JT_CHUNK 16                     // pocket rows per block
#define ZP_STRIDE 132                   // 128 + 4 f32 pad (bank spread)

#define EDGE_BLOCKS (B_CPLX * 10)       // 1280 = (b, jt)

#define NEG_LOG2E -1.4426950408889634f  // -log2(e)
#define NEG_LN2   -0.69314718055994531f // -ln(2)

typedef __bf16 bf16x8 __attribute__((ext_vector_type(8)));
typedef __bf16 bf16x2 __attribute__((ext_vector_type(2)));
typedef unsigned short ushortx8 __attribute__((ext_vector_type(8)));
typedef unsigned short ushortx4 __attribute__((ext_vector_type(4)));
typedef unsigned uintx4 __attribute__((ext_vector_type(4)));
typedef float f32x4 __attribute__((ext_vector_type(4)));
typedef float f32x2 __attribute__((ext_vector_type(2)));

#if __has_builtin(__builtin_amdgcn_exp2f)
#define EXP2F(x) __builtin_amdgcn_exp2f(x)
#else
#define EXP2F(x) exp2f(x)
#endif

__device__ __forceinline__ unsigned short f2bf(float f) {
    unsigned u = __builtin_bit_cast(unsigned, f);
    u += 0x7FFFu + ((u >> 16) & 1u);          // round-to-nearest-even
    return (unsigned short)(u >> 16);
}

// v_perm_b32: pack hi16(x0) low, hi16(x1) high (1 op)
__device__ __forceinline__ unsigned perm_hi16u(unsigned u0, unsigned u1) {
    return __builtin_amdgcn_perm(u1, u0, 0x07060302u);
}

// round-half-up bf16 pair pack: bitpattern + 0x8000 then take hi16.
__device__ __forceinline__ unsigned pack2_rhu(float x0, float x1) {
    unsigned u0 = __builtin_bit_cast(unsigned, x0) + 0x8000u;
    unsigned u1 = __builtin_bit_cast(unsigned, x1) + 0x8000u;
    return perm_hi16u(u0, u1);
}

// RNE pack via HW v_cvt_pk_bf16_f32 (compiler-lowered, no inline asm)
__device__ __forceinline__ bf16x8 pack8_rne(const float* x) {
    bf16x8 r;
#pragma unroll
    for (int j = 0; j < 4; ++j) {
        f32x2 p = {x[2 * j], x[2 * j + 1]};
        bf16x2 b = __builtin_convertvector(p, bf16x2);
        r[2 * j]     = b[0];
        r[2 * j + 1] = b[1];
    }
    return r;
}

// hi/lo exact split (proj only): hi = trunc bf16, lo = bf16(x - hi)
__device__ __forceinline__ void pack_split(const float* x, bf16x8& hi, bf16x8& lo) {
    uintx4 h, l;
#pragma unroll
    for (int j = 0; j < 4; ++j) {
        float x0 = x[2 * j], x1 = x[2 * j + 1];
        unsigned u0 = __builtin_bit_cast(unsigned, x0);
        unsigned u1 = __builtin_bit_cast(unsigned, x1);
        h[j] = perm_hi16u(u0, u1);
        float hf0 = __builtin_bit_cast(float, u0 & 0xFFFF0000u);
        float hf1 = __builtin_bit_cast(float, u1 & 0xFFFF0000u);
        l[j] = pack2_rhu(x0 - hf0, x1 - hf1);
    }
    hi = __builtin_bit_cast(bf16x8, h);
    lo = __builtin_bit_cast(bf16x8, l);
}

// pre-scaled silu: t = -log2e * s  ->  u = t * sigma(s) = -log2e * silu(s)
__device__ __forceinline__ float silu_u(float t) {
    float e = EXP2F(t);
    float r = __builtin_amdgcn_rcpf(1.0f + e);
    return t * r;
}

// ---------------------------------------------------------------------------
// Kernel 1: Z[m][n] = -log2e * (X[m] @ W1[n] (+ b1[n] if ligand row))
//   W1 scaled BEFORE bf16 rounding -> no extra ops; hi/lo split on X exact.
//   Block 0 additionally writes the fragment-ordered bf16 W2 (16 KB,
//   unscaled RNE) to the workspace region after Z.
// ---------------------------------------------------------------------------
__global__ __launch_bounds__(256) void proj_kernel(
    const float* __restrict__ s_lig, const float* __restrict__ s_poc,
    const float* __restrict__ W1,    const float* __restrict__ b1,
    const float* __restrict__ W2,
    float* __restrict__ Z,           unsigned short* __restrict__ W2F)
{
    __shared__ unsigned short w1s[64 * W1_LDS_STRIDE];   // 33.8 KB

    const int tid  = threadIdx.x;
    const int tg   = blockIdx.x >> 1;             // row-tile group 0..383
    const int half = blockIdx.x & 1;              // N half

    // block 0 extra duty: frag-ordered bf16 W2 -> workspace (v21 values)
    if (blockIdx.x == 0) {
#pragma unroll
        for (int s = 0; s < 4; ++s) {
            const int slot   = tid + s * 256;             // 0..1023
            const int lane_s = slot & 63;
            const int chunk  = slot >> 6;
            const int nt     = chunk >> 2;
            const int ks     = chunk & 3;
            const int n      = nt * 16 + (lane_s & 15);
            const int k0     = ks * 32 + (lane_s >> 4) * 8;
            const float* wsrc = W2 + (size_t)n * H1DIM + k0;
            f32x4 wa = *(const f32x4*)wsrc;
            f32x4 wb = *(const f32x4*)(wsrc + 4);
            ushortx8 us;
#pragma unroll
            for (int j = 0; j < 4; ++j) {
                us[j]     = f2bf(wa[j]);
                us[4 + j] = f2bf(wb[j]);
            }
            *(ushortx8*)(&W2F[slot * 8]) = us;
        }
    }

    {
        const f32x4* w4 = (const f32x4*)(W1 + (size_t)half * 64 * SDIM);  // 4096 units
#pragma unroll
        for (int r = 0; r < 2; ++r) {
            f32x4 t[8];
#pragma unroll
            for (int s = 0; s < 8; ++s) t[s] = w4[tid + (r * 8 + s) * 256];
#pragma unroll
            for (int s = 0; s < 8; ++s) {
                const int u = tid + (r * 8 + s) * 256;
                const int n = u >> 6;             // 64 f32x4 per 256-col row
                const int k4 = u & 63;
                ushortx4 us;
#pragma unroll
                for (int j = 0; j < 4; ++j) us[j] = f2bf(t[s][j] * NEG_LOG2E);
                *(ushortx4*)(&w1s[n * W1_LDS_STRIDE + k4 * 4]) = us;
            }
        }
    }
    __syncthreads();

    const int lane = tid & 63;
    const int widx = tid >> 6;
    const int c    = lane & 15;
    const int q    = lane >> 4;
    const int tile = tg * 4 + widx;               // 0..1535
    const int row  = tile * 16 + c;

    const float* src = (row < NL_TOT) ? (s_lig + (size_t)row * SDIM)
                                      : (s_poc + (size_t)(row - NL_TOT) * SDIM);

    f32x4 acc[4];
#pragma unroll
    for (int nt = 0; nt < 4; ++nt) acc[nt] = (f32x4){0.f, 0.f, 0.f, 0.f};

#pragma unroll
    for (int ks = 0; ks < 8; ++ks) {              // K = 256 = 8 x 32
        const int k0 = ks * 32 + q * 8;
        f32x4 xa = *reinterpret_cast<const f32x4*>(src + k0);
        f32x4 xb = *reinterpret_cast<const f32x4*>(src + k0 + 4);
        float xv[8] = {xa[0], xa[1], xa[2], xa[3], xb[0], xb[1], xb[2], xb[3]};
        bf16x8 ahi, alo;
        pack_split(xv, ahi, alo);
        bf16x8 bfrag[4];
#pragma unroll
        for (int nt = 0; nt < 4; ++nt)
            bfrag[nt] = *reinterpret_cast<const bf16x8*>(
                &w1s[(nt * 16 + c) * W1_LDS_STRIDE + k0]);
#pragma unroll
        for (int nt = 0; nt < 4; ++nt)            // hi pass (dep distance 4)
            acc[nt] = __builtin_amdgcn_mfma_f32_16x16x32_bf16(ahi, bfrag[nt], acc[nt], 0, 0, 0);
#pragma unroll
        for (int nt = 0; nt < 4; ++nt)            // lo pass
            acc[nt] = __builtin_amdgcn_mfma_f32_16x16x32_bf16(alo, bfrag[nt], acc[nt], 0, 0, 0);
    }

    // C/D layout: col n' = lane&15, row m = q*4 + reg
    const int mb = tile * 16 + q * 4;
#pragma unroll
    for (int nt = 0; nt < 4; ++nt) {
        const int n = half * 64 + nt * 16 + c;
        const float bias = b1[n] * NEG_LOG2E;     // scaled bias (Z pre-scaled)
#pragma unroll
        for (int r = 0; r < 4; ++r) {
            const int m = mb + r;
            float v = acc[nt][r];
            if (m < NL_TOT) v += bias;            // fold b1 into ligand rows only
            Z[(size_t)m * H1DIM + n] = v;
        }
    }
}

// ---------------------------------------------------------------------------
// Kernel 2: block = (complex b, pocket chunk jt); 1280 blocks x 4 waves.
//   Staging = pure copies (Z pre-scaled; W2F pre-converted). 2 h-iters x
//   4 atoms per wave. SWAPPED MFMA: acc = D^T -> lane holds h2 channels
//   m = nt*16+q*4+r for pocket c; epilogue = fma dot + 2 shfl_xor.
// ---------------------------------------------------------------------------
__global__ __launch_bounds__(256) void edge_kernel(
    const float* __restrict__ Z,  const unsigned short* __restrict__ W2F,
    const float* __restrict__ b2, const float* __restrict__ W3,
    const float* __restrict__ b3, float* __restrict__ out)
{
    __shared__ float zp[JT_CHUNK * ZP_STRIDE];            // 8.4 KB (pre-scaled)
    __shared__ float zl[NLB * H1DIM];                     // 16 KB (pre-scaled)
    __shared__ unsigned short w2s[16 * 64 * 8];           // 16 KB frag-ordered

    const int tid = threadIdx.x;
    const int b   = blockIdx.x / 10;
    const int jt  = blockIdx.x - b * 10;          // 0..9

    // stage W2 fragments: pure 16B copies from the precomputed region
    {
#pragma unroll
        for (int s = 0; s < 4; ++s) {
            const int slot = tid + s * 256;               // 0..1023
            *(ushortx8*)(&w2s[slot * 8]) = *(const ushortx8*)(&W2F[slot * 8]);
        }
    }

    // stage pocket rows (pre-scaled): pure copy, 2 f32x4 per thread
    {
        const float* zpg = Z + (size_t)(NL_TOT + b * NPB + jt * JT_CHUNK) * H1DIM;
#pragma unroll
        for (int s = 0; s < 2; ++s) {
            const int u   = tid + s * 256;
            const int row = u >> 5;
            const int c4  = u & 31;
            *(f32x4*)(&zp[row * ZP_STRIDE + c4 * 4]) =
                *(const f32x4*)(zpg + (size_t)row * H1DIM + c4 * 4);
        }
    }

    // stage ALL 32 ligand rows (pre-scaled): pure copy, 4 f32x4 per thread
    {
        const float* zlg = Z + (size_t)(b * NLB) * H1DIM;
#pragma unroll
        for (int s = 0; s < 4; ++s) {
            const int u   = tid + s * 256;                // 0..1023
            const int row = u >> 5;
            const int c4  = u & 31;
            *(f32x4*)(&zl[row * H1DIM + c4 * 4]) =
                *(const f32x4*)(zlg + (size_t)row * H1DIM + c4 * 4);
        }
    }

    const int lane = tid & 63;
    const int widx = tid >> 6;
    const int c    = lane & 15;
    const int q    = lane >> 4;

    // swapped-D layout: lane reg (nt, r) <-> h2 channel m = nt*16 + q*4 + r.
    // b2 scaled by -log2e (acc accumulates t2); W3 scaled by -ln2.
    f32x4 b2v[4], w3v[4];
#pragma unroll
    for (int nt = 0; nt < 4; ++nt) {
        f32x4 bv = *(const f32x4*)(b2 + nt * 16 + q * 4);
        f32x4 wv = *(const f32x4*)(W3 + nt * 16 + q * 4);
        b2v[nt] = bv * NEG_LOG2E;
        w3v[nt] = wv * NEG_LN2;
    }
    const float b3v = b3[0];

    __syncthreads();   // w2s + zp + zl visible; the ONLY barrier

    const float* prow = &zp[c * ZP_STRIDE];
    const unsigned short* wbase = &w2s[lane * 8];          // + chunk*512 ushorts

#pragma unroll
    for (int h = 0; h < 2; ++h) {                  // atom groups of 16
        // acc init = -log2e * b2 (per-channel, vectorized over r)
        f32x4 acc[4][4];                           // [atom][nt]
#pragma unroll
        for (int a = 0; a < 4; ++a)
#pragma unroll
            for (int nt = 0; nt < 4; ++nt) acc[a][nt] = b2v[nt];

        // wave's 4 atoms this group: h*16 + widx*4 + a
        const float* lrow0 = &zl[(h * 16 + widx * 4) * H1DIM];

#pragma unroll
        for (int ks = 0; ks < 4; ++ks) {           // K = 128 = 4 x 32
            const int k0 = ks * 32 + q * 8;
            bf16x8 bfr[4];
#pragma unroll
            for (int nt = 0; nt < 4; ++nt)         // conflict-free ds_read_b128
                bfr[nt] = *(const bf16x8*)(wbase + (nt * 4 + ks) * 512);
            f32x4 pa = *(const f32x4*)(prow + k0);
            f32x4 pb = *(const f32x4*)(prow + k0 + 4);
#pragma unroll
            for (int a = 0; a < 4; ++a) {          // 4 atoms share bfr/pa/pb
                f32x4 la0 = *(const f32x4*)(lrow0 + a * H1DIM + k0);
                f32x4 la1 = *(const f32x4*)(lrow0 + a * H1DIM + k0 + 4);
                float hv[8];
#pragma unroll
                for (int j = 0; j < 4; ++j) {      // u = -log2e * silu(s)
                    hv[j]     = silu_u(pa[j] + la0[j]);
                    hv[4 + j] = silu_u(pb[j] + la1[j]);
                }
                bf16x8 af = pack8_rne(hv);
#pragma unroll
                for (int nt = 0; nt < 4; ++nt)     // SWAPPED: D^T, bitwise
                    acc[a][nt] = __builtin_amdgcn_mfma_f32_16x16x32_bf16(bfr[nt], af, acc[a][nt], 0, 0, 0);
            }
        }

        // epilogue: lane holds t2 for channels m=nt*16+q*4+r, pocket c.
        // dot(silu_u(t2), w3v) per lane -> sum over q via shfl_xor 16/32.
#pragma unroll
        for (int at = 0; at < 4; ++at) {
            const f32x4* A = acc[at];
            float s0 = 0.f, s1 = 0.f, s2 = 0.f, s3 = 0.f;
#pragma unroll
            for (int nt = 0; nt < 4; ++nt) {       // u2 = -log2e*silu(h2pre)
                s0 += silu_u(A[nt][0]) * w3v[nt][0];
                s1 += silu_u(A[nt][1]) * w3v[nt][1];
                s2 += silu_u(A[nt][2]) * w3v[nt][2];
                s3 += silu_u(A[nt][3]) * w3v[nt][3];
            }
            float v = (s0 + s1) + (s2 + s3);       // per-lane partial (16 ch)
            v += __shfl_xor(v, 16);                // q ^ 1
            v += __shfl_xor(v, 32);                // q ^ 2 -> all 64 channels
            if (lane < 16) {
                const int e0 = (b * NLB + h * 16 + widx * 4 + at) * NPB + jt * JT_CHUNK;
                out[e0 + lane] = fmaxf(v + b3v, 0.0f);   // 64B coalesced
            }
        }
    }
}

// ---------------------------------------------------------------------------
extern "C" void kernel_launch(void* const* d_in, const int* in_sizes, int n_in,
                              void* d_out, int out_size, void* d_ws, size_t ws_size,
                              hipStream_t stream)
{
    const float* s_lig = (const float*)d_in[0];
    const float* s_poc = (const float*)d_in[1];
    const float* W1    = (const float*)d_in[4];
    const float* b1    = (const float*)d_in[5];
    const float* W2    = (const float*)d_in[6];
    const float* b2    = (const float*)d_in[7];
    const float* W3    = (const float*)d_in[8];
    const float* b3    = (const float*)d_in[9];

    float* Z = (float*)d_ws;                       // 12.58 MB (pre-scaled Z)
    unsigned short* W2F = (unsigned short*)(Z + (size_t)NROWS * H1DIM);  // +16 KB

    hipLaunchKernelGGL(proj_kernel, dim3(NROWS / 16 / 4 * 2), dim3(256), 0, stream,
                       s_lig, s_poc, W1, b1, W2, Z, W2F);
    hipLaunchKernelGGL(edge_kernel, dim3(EDGE_BLOCKS), dim3(256), 0, stream,
                       Z, W2F, b2, W3, b3, (float*)d_out);
}

// Round 11
// 126.400 us; speedup vs baseline: 1.1219x; 1.0312x over previous
//
#include <hip/hip_runtime.h>
#include <hip/hip_bf16.h>

// ---------------------------------------------------------------------------
// HiddenEdgeDistanceMLP on MI355X (gfx950)
//
// reference:  s = s_lig[l] + s_poc[p]          [E,256]
//             h1 = silu(s @ W1.T + b1)         [E,128]
//             h2 = silu(h1 @ W2.T + b2)        [E,64]
//             out = relu(h2 @ W3.T + b3)       [E]
//
// v23 (R10): two independent cuts (one per kernel, attributable):
//   EDGE: 512-thread blocks (8 waves), h-loop removed — each wave does its
//     4 atoms in ONE pass. Same math, same LDS (41.5KB serves all 8 waves),
//     same per-wave inventory; residency 12 -> up to 24 waves/CU. Unlike
//     R6's regression this adds NO scattered loads — clean residency test.
//   PROJ: all bf16 conversions via v_cvt_pk_bf16_f32 (__builtin_convertvector,
//     RNE — bitwise identical to f2bf for W1/W2F) instead of 3-op f2bf per
//     element; pack_split lo-path RHU -> cvt RNE (<=2^-17 perturbation of Z).
//     Staging VALU ~3x cheaper; W1 pre-scaled x(-log2e) as in v22.
// v22 mechanisms kept: Z pre-scaled, W2F pre-converted (block 0), swapped
//   D^T MFMA epilogue (fma dot + 2 shfl_xor, coalesced 64B stores), exp2
//   silu everywhere, RNE cvt_pk pack, block=(b,jt) grid 1280, one barrier.
// ---------------------------------------------------------------------------

#define B_CPLX   128
#define NLB      32
#define NPB      160
#define SDIM     256
#define H1DIM    128
#define NL_TOT   (B_CPLX * NLB)         // 4096
#define NP_TOT   (B_CPLX * NPB)         // 20480
#define NROWS    (NL_TOT + NP_TOT)      // 24576
#define E_TOT    (B_CPLX * NLB * NPB)   // 655360

#define W1_LDS_STRIDE 264               // 256 + 8 bf16 pad
#define JT_CHUNK 16                     // pocket rows per block
#define ZP_STRIDE 132                   // 128 + 4 f32 pad (bank spread)

#define EDGE_BLOCKS (B_CPLX * 10)       // 1280 = (b, jt)

#define NEG_LOG2E -1.4426950408889634f  // -log2(e)
#define NEG_LN2   -0.69314718055994531f // -ln(2)

typedef __bf16 bf16x8 __attribute__((ext_vector_type(8)));
typedef __bf16 bf16x2 __attribute__((ext_vector_type(2)));
typedef unsigned short ushortx8 __attribute__((ext_vector_type(8)));
typedef unsigned short ushortx4 __attribute__((ext_vector_type(4)));
typedef unsigned uintx4 __attribute__((ext_vector_type(4)));
typedef unsigned uintx2 __attribute__((ext_vector_type(2)));
typedef float f32x4 __attribute__((ext_vector_type(4)));
typedef float f32x2 __attribute__((ext_vector_type(2)));

#if __has_builtin(__builtin_amdgcn_exp2f)
#define EXP2F(x) __builtin_amdgcn_exp2f(x)
#else
#define EXP2F(x) exp2f(x)
#endif

// v_perm_b32: pack hi16(x0) low, hi16(x1) high (1 op)
__device__ __forceinline__ unsigned perm_hi16u(unsigned u0, unsigned u1) {
    return __builtin_amdgcn_perm(u1, u0, 0x07060302u);
}

// RNE pair-convert via HW v_cvt_pk_bf16_f32 -> packed u32
__device__ __forceinline__ unsigned cvt2_rne(float x0, float x1) {
    f32x2 p = {x0, x1};
    bf16x2 b = __builtin_convertvector(p, bf16x2);
    return __builtin_bit_cast(unsigned, b);
}

// f32x4 -> 4 bf16 (RNE, 2 cvt_pk ops), as uintx2 for a ds_write_b64
__device__ __forceinline__ uintx2 pack4_rne_u(f32x4 v) {
    uintx2 r;
    r[0] = cvt2_rne(v[0], v[1]);
    r[1] = cvt2_rne(v[2], v[3]);
    return r;
}

// RNE pack of 8 floats via cvt_pk (compiler-lowered, no inline asm)
__device__ __forceinline__ bf16x8 pack8_rne(const float* x) {
    uintx4 h;
#pragma unroll
    for (int j = 0; j < 4; ++j) h[j] = cvt2_rne(x[2 * j], x[2 * j + 1]);
    return __builtin_bit_cast(bf16x8, h);
}

// hi/lo split (proj only): hi = trunc bf16 (perm), lo = RNE bf16(x - hi)
__device__ __forceinline__ void pack_split(const float* x, bf16x8& hi, bf16x8& lo) {
    uintx4 h, l;
#pragma unroll
    for (int j = 0; j < 4; ++j) {
        float x0 = x[2 * j], x1 = x[2 * j + 1];
        unsigned u0 = __builtin_bit_cast(unsigned, x0);
        unsigned u1 = __builtin_bit_cast(unsigned, x1);
        h[j] = perm_hi16u(u0, u1);
        float hf0 = __builtin_bit_cast(float, u0 & 0xFFFF0000u);
        float hf1 = __builtin_bit_cast(float, u1 & 0xFFFF0000u);
        l[j] = cvt2_rne(x0 - hf0, x1 - hf1);
    }
    hi = __builtin_bit_cast(bf16x8, h);
    lo = __builtin_bit_cast(bf16x8, l);
}

// pre-scaled silu: t = -log2e * s  ->  u = t * sigma(s) = -log2e * silu(s)
__device__ __forceinline__ float silu_u(float t) {
    float e = EXP2F(t);
    float r = __builtin_amdgcn_rcpf(1.0f + e);
    return t * r;
}

// ---------------------------------------------------------------------------
// Kernel 1: Z[m][n] = -log2e * (X[m] @ W1[n] (+ b1[n] if ligand row))
//   W1 scaled BEFORE bf16 rounding; hi/lo split on X keeps Z near-exact.
//   Block 0 additionally writes the fragment-ordered bf16 W2 (16 KB,
//   unscaled RNE) to the workspace region after Z.
// ---------------------------------------------------------------------------
__global__ __launch_bounds__(256) void proj_kernel(
    const float* __restrict__ s_lig, const float* __restrict__ s_poc,
    const float* __restrict__ W1,    const float* __restrict__ b1,
    const float* __restrict__ W2,
    float* __restrict__ Z,           unsigned short* __restrict__ W2F)
{
    __shared__ unsigned short w1s[64 * W1_LDS_STRIDE];   // 33.8 KB

    const int tid  = threadIdx.x;
    const int tg   = blockIdx.x >> 1;             // row-tile group 0..383
    const int half = blockIdx.x & 1;              // N half

    // block 0 extra duty: frag-ordered bf16 W2 -> workspace (RNE = f2bf bits)
    if (blockIdx.x == 0) {
#pragma unroll
        for (int s = 0; s < 4; ++s) {
            const int slot   = tid + s * 256;             // 0..1023
            const int lane_s = slot & 63;
            const int chunk  = slot >> 6;
            const int nt     = chunk >> 2;
            const int ks     = chunk & 3;
            const int n      = nt * 16 + (lane_s & 15);
            const int k0     = ks * 32 + (lane_s >> 4) * 8;
            const float* wsrc = W2 + (size_t)n * H1DIM + k0;
            f32x4 wa = *(const f32x4*)wsrc;
            f32x4 wb = *(const f32x4*)(wsrc + 4);
            uintx4 us;
            us[0] = cvt2_rne(wa[0], wa[1]);
            us[1] = cvt2_rne(wa[2], wa[3]);
            us[2] = cvt2_rne(wb[0], wb[1]);
            us[3] = cvt2_rne(wb[2], wb[3]);
            *(uintx4*)(&W2F[slot * 8]) = us;
        }
    }

    {
        const f32x4* w4 = (const f32x4*)(W1 + (size_t)half * 64 * SDIM);  // 4096 units
#pragma unroll
        for (int r = 0; r < 2; ++r) {
            f32x4 t[8];
#pragma unroll
            for (int s = 0; s < 8; ++s) t[s] = w4[tid + (r * 8 + s) * 256];
#pragma unroll
            for (int s = 0; s < 8; ++s) {
                const int u = tid + (r * 8 + s) * 256;
                const int n = u >> 6;             // 64 f32x4 per 256-col row
                const int k4 = u & 63;
                uintx2 us = pack4_rne_u(t[s] * NEG_LOG2E);   // 2 cvt_pk + 1 pk-mul
                *(uintx2*)(&w1s[n * W1_LDS_STRIDE + k4 * 4]) = us;
            }
        }
    }
    __syncthreads();

    const int lane = tid & 63;
    const int widx = tid >> 6;
    const int c    = lane & 15;
    const int q    = lane >> 4;
    const int tile = tg * 4 + widx;               // 0..1535
    const int row  = tile * 16 + c;

    const float* src = (row < NL_TOT) ? (s_lig + (size_t)row * SDIM)
                                      : (s_poc + (size_t)(row - NL_TOT) * SDIM);

    f32x4 acc[4];
#pragma unroll
    for (int nt = 0; nt < 4; ++nt) acc[nt] = (f32x4){0.f, 0.f, 0.f, 0.f};

#pragma unroll
    for (int ks = 0; ks < 8; ++ks) {              // K = 256 = 8 x 32
        const int k0 = ks * 32 + q * 8;
        f32x4 xa = *reinterpret_cast<const f32x4*>(src + k0);
        f32x4 xb = *reinterpret_cast<const f32x4*>(src + k0 + 4);
        float xv[8] = {xa[0], xa[1], xa[2], xa[3], xb[0], xb[1], xb[2], xb[3]};
        bf16x8 ahi, alo;
        pack_split(xv, ahi, alo);
        bf16x8 bfrag[4];
#pragma unroll
        for (int nt = 0; nt < 4; ++nt)
            bfrag[nt] = *reinterpret_cast<const bf16x8*>(
                &w1s[(nt * 16 + c) * W1_LDS_STRIDE + k0]);
#pragma unroll
        for (int nt = 0; nt < 4; ++nt)            // hi pass (dep distance 4)
            acc[nt] = __builtin_amdgcn_mfma_f32_16x16x32_bf16(ahi, bfrag[nt], acc[nt], 0, 0, 0);
#pragma unroll
        for (int nt = 0; nt < 4; ++nt)            // lo pass
            acc[nt] = __builtin_amdgcn_mfma_f32_16x16x32_bf16(alo, bfrag[nt], acc[nt], 0, 0, 0);
    }

    // C/D layout: col n' = lane&15, row m = q*4 + reg
    const int mb = tile * 16 + q * 4;
#pragma unroll
    for (int nt = 0; nt < 4; ++nt) {
        const int n = half * 64 + nt * 16 + c;
        const float bias = b1[n] * NEG_LOG2E;     // scaled bias (Z pre-scaled)
#pragma unroll
        for (int r = 0; r < 4; ++r) {
            const int m = mb + r;
            float v = acc[nt][r];
            if (m < NL_TOT) v += bias;            // fold b1 into ligand rows only
            Z[(size_t)m * H1DIM + n] = v;
        }
    }
}

// ---------------------------------------------------------------------------
// Kernel 2: block = (complex b, pocket chunk jt); 1280 blocks x 512 threads
//   (8 waves). Wave widx owns atoms widx*4..widx*4+3, single pass. Staging
//   split over 8 waves; one barrier; SWAPPED D^T MFMA epilogue.
// ---------------------------------------------------------------------------
__global__ __launch_bounds__(512) void edge_kernel(
    const float* __restrict__ Z,  const unsigned short* __restrict__ W2F,
    const float* __restrict__ b2, const float* __restrict__ W3,
    const float* __restrict__ b3, float* __restrict__ out)
{
    __shared__ float zp[JT_CHUNK * ZP_STRIDE];            // 8.4 KB (pre-scaled)
    __shared__ float zl[NLB * H1DIM];                     // 16 KB (pre-scaled)
    __shared__ unsigned short w2s[16 * 64 * 8];           // 16 KB frag-ordered

    const int tid = threadIdx.x;                  // 0..511
    const int b   = blockIdx.x / 10;
    const int jt  = blockIdx.x - b * 10;          // 0..9

    // stage W2 fragments: pure 16B copies from the precomputed region
    {
#pragma unroll
        for (int s = 0; s < 2; ++s) {
            const int slot = tid + s * 512;               // 0..1023
            *(ushortx8*)(&w2s[slot * 8]) = *(const ushortx8*)(&W2F[slot * 8]);
        }
    }

    // stage pocket rows (pre-scaled): pure copy, 1 f32x4 per thread
    {
        const float* zpg = Z + (size_t)(NL_TOT + b * NPB + jt * JT_CHUNK) * H1DIM;
        const int row = tid >> 5;
        const int c4  = tid & 31;
        *(f32x4*)(&zp[row * ZP_STRIDE + c4 * 4]) =
            *(const f32x4*)(zpg + (size_t)row * H1DIM + c4 * 4);
    }

    // stage ALL 32 ligand rows (pre-scaled): pure copy, 2 f32x4 per thread
    {
        const float* zlg = Z + (size_t)(b * NLB) * H1DIM;
#pragma unroll
        for (int s = 0; s < 2; ++s) {
            const int u   = tid + s * 512;                // 0..1023
            const int row = u >> 5;
            const int c4  = u & 31;
            *(f32x4*)(&zl[row * H1DIM + c4 * 4]) =
                *(const f32x4*)(zlg + (size_t)row * H1DIM + c4 * 4);
        }
    }

    const int lane = tid & 63;
    const int widx = tid >> 6;                    // 0..7
    const int c    = lane & 15;
    const int q    = lane >> 4;

    // swapped-D layout: lane reg (nt, r) <-> h2 channel m = nt*16 + q*4 + r.
    // b2 scaled by -log2e (acc accumulates t2); W3 scaled by -ln2.
    f32x4 b2v[4], w3v[4];
#pragma unroll
    for (int nt = 0; nt < 4; ++nt) {
        f32x4 bv = *(const f32x4*)(b2 + nt * 16 + q * 4);
        f32x4 wv = *(const f32x4*)(W3 + nt * 16 + q * 4);
        b2v[nt] = bv * NEG_LOG2E;
        w3v[nt] = wv * NEG_LN2;
    }
    const float b3v = b3[0];

    __syncthreads();   // w2s + zp + zl visible; the ONLY barrier

    const float* prow = &zp[c * ZP_STRIDE];
    const unsigned short* wbase = &w2s[lane * 8];          // + chunk*512 ushorts

    // acc init = -log2e * b2 (per-channel, vectorized over r)
    f32x4 acc[4][4];                               // [atom][nt]
#pragma unroll
    for (int a = 0; a < 4; ++a)
#pragma unroll
        for (int nt = 0; nt < 4; ++nt) acc[a][nt] = b2v[nt];

    // wave's 4 atoms: widx*4 + a
    const float* lrow0 = &zl[(widx * 4) * H1DIM];

#pragma unroll
    for (int ks = 0; ks < 4; ++ks) {               // K = 128 = 4 x 32
        const int k0 = ks * 32 + q * 8;
        bf16x8 bfr[4];
#pragma unroll
        for (int nt = 0; nt < 4; ++nt)             // conflict-free ds_read_b128
            bfr[nt] = *(const bf16x8*)(wbase + (nt * 4 + ks) * 512);
        f32x4 pa = *(const f32x4*)(prow + k0);
        f32x4 pb = *(const f32x4*)(prow + k0 + 4);
#pragma unroll
        for (int a = 0; a < 4; ++a) {              // 4 atoms share bfr/pa/pb
            f32x4 la0 = *(const f32x4*)(lrow0 + a * H1DIM + k0);
            f32x4 la1 = *(const f32x4*)(lrow0 + a * H1DIM + k0 + 4);
            float hv[8];
#pragma unroll
            for (int j = 0; j < 4; ++j) {          // u = -log2e * silu(s)
                hv[j]     = silu_u(pa[j] + la0[j]);
                hv[4 + j] = silu_u(pb[j] + la1[j]);
            }
            bf16x8 af = pack8_rne(hv);
#pragma unroll
            for (int nt = 0; nt < 4; ++nt)         // SWAPPED: D^T, bitwise
                acc[a][nt] = __builtin_amdgcn_mfma_f32_16x16x32_bf16(bfr[nt], af, acc[a][nt], 0, 0, 0);
        }
    }

    // epilogue: lane holds t2 for channels m=nt*16+q*4+r, pocket c.
    // dot(silu_u(t2), w3v) per lane -> sum over q via shfl_xor 16/32.
#pragma unroll
    for (int at = 0; at < 4; ++at) {
        const f32x4* A = acc[at];
        float s0 = 0.f, s1 = 0.f, s2 = 0.f, s3 = 0.f;
#pragma unroll
        for (int nt = 0; nt < 4; ++nt) {           // u2 = -log2e*silu(h2pre)
            s0 += silu_u(A[nt][0]) * w3v[nt][0];
            s1 += silu_u(A[nt][1]) * w3v[nt][1];
            s2 += silu_u(A[nt][2]) * w3v[nt][2];
            s3 += silu_u(A[nt][3]) * w3v[nt][3];
        }
        float v = (s0 + s1) + (s2 + s3);           // per-lane partial (16 ch)
        v += __shfl_xor(v, 16);                    // q ^ 1
        v += __shfl_xor(v, 32);                    // q ^ 2 -> all 64 channels
        if (lane < 16) {
            const int e0 = (b * NLB + widx * 4 + at) * NPB + jt * JT_CHUNK;
            out[e0 + lane] = fmaxf(v + b3v, 0.0f); // 64B coalesced
        }
    }
}

// ---------------------------------------------------------------------------
extern "C" void kernel_launch(void* const* d_in, const int* in_sizes, int n_in,
                              void* d_out, int out_size, void* d_ws, size_t ws_size,
                              hipStream_t stream)
{
    const float* s_lig = (const float*)d_in[0];
    const float* s_poc = (const float*)d_in[1];
    const float* W1    = (const float*)d_in[4];
    const float* b1    = (const float*)d_in[5];
    const float* W2    = (const float*)d_in[6];
    const float* b2    = (const float*)d_in[7];
    const float* W3    = (const float*)d_in[8];
    const float* b3    = (const float*)d_in[9];

    float* Z = (float*)d_ws;                       // 12.58 MB (pre-scaled Z)
    unsigned short* W2F = (unsigned short*)(Z + (size_t)NROWS * H1DIM);  // +16 KB

    hipLaunchKernelGGL(proj_kernel, dim3(NROWS / 16 / 4 * 2), dim3(256), 0, stream,
                       s_lig, s_poc, W1, b1, W2, Z, W2F);
    hipLaunchKernelGGL(edge_kernel, dim3(EDGE_BLOCKS), dim3(512), 0, stream,
                       Z, W2F, b2, W3, b3, (float*)d_out);
}